// Round 1
// baseline (568.928 us; speedup 1.0000x reference)
//
#include <hip/hip_runtime.h>

#define NPOS 16384   // D*H*W = 16*32*32
#define CDIM 64

typedef short bf16x8 __attribute__((ext_vector_type(8)));   // 8 bf16 in 4 VGPRs
typedef float floatx4 __attribute__((ext_vector_type(4)));

// ---------------------------------------------------------------------------
// Projection kernel: q[8], k[8] (fp32, [n][8] packed) and v (bf16, [c][n])
// One thread per position n; x column register-cached; weights via scalar loads.
// ---------------------------------------------------------------------------
__global__ __launch_bounds__(64) void proj_kernel(
    const float* __restrict__ x,
    const float* __restrict__ wq, const float* __restrict__ bq,
    const float* __restrict__ wk, const float* __restrict__ bk,
    const float* __restrict__ wv, const float* __restrict__ bv,
    float* __restrict__ qbuf, float* __restrict__ kbuf,
    unsigned short* __restrict__ vbuf)
{
    const int n = blockIdx.x * 64 + threadIdx.x;

    float xr[64];
#pragma unroll
    for (int c = 0; c < 64; ++c) xr[c] = x[c * NPOS + n];

    float qv[8], kv[8];
#pragma unroll
    for (int o = 0; o < 8; ++o) {
        const float* w = wq + o * 64;
        float s = bq[o];
#pragma unroll
        for (int c = 0; c < 64; ++c) s = fmaf(w[c], xr[c], s);
        qv[o] = s;
    }
#pragma unroll
    for (int o = 0; o < 8; ++o) {
        const float* w = wk + o * 64;
        float s = bk[o];
#pragma unroll
        for (int c = 0; c < 64; ++c) s = fmaf(w[c], xr[c], s);
        kv[o] = s;
    }
    {
        floatx4 a = {qv[0], qv[1], qv[2], qv[3]};
        floatx4 b = {qv[4], qv[5], qv[6], qv[7]};
        *(floatx4*)(qbuf + (size_t)n * 8)     = a;
        *(floatx4*)(qbuf + (size_t)n * 8 + 4) = b;
    }
    {
        floatx4 a = {kv[0], kv[1], kv[2], kv[3]};
        floatx4 b = {kv[4], kv[5], kv[6], kv[7]};
        *(floatx4*)(kbuf + (size_t)n * 8)     = a;
        *(floatx4*)(kbuf + (size_t)n * 8 + 4) = b;
    }
    // v projection: store bf16 (truncation is plenty; values feed bf16 MFMA anyway)
#pragma unroll 2
    for (int o = 0; o < 64; ++o) {
        const float* w = wv + o * 64;
        float s = bv[o];
#pragma unroll
        for (int c = 0; c < 64; ++c) s = fmaf(w[c], xr[c], s);
        vbuf[(size_t)o * NPOS + n] =
            (unsigned short)(__builtin_bit_cast(unsigned int, s) >> 16);
    }
}

// ---------------------------------------------------------------------------
// Attention kernel. 256 blocks x 256 threads (4 waves). Block = 64 queries,
// wave = 16 queries. Key loop: chunks of 256 keys staged to LDS, inner steps
// of 32 keys = one MFMA K-slab.
//   scores: vector fp32, lane computes its own A-frag (query m=l&15,
//           keys kbase=(l>>4)*8 .. +7)  -> exp -> bf16 pack in registers.
//   PV:     4x v_mfma_f32_16x16x32_bf16 per step (channel tiles of 16).
//   softmax: max-free (scores tiny, |s| << 1); den reduced via shfl_xor.
// ---------------------------------------------------------------------------
__global__ __launch_bounds__(256) void attn_kernel(
    const float* __restrict__ x,
    const float* __restrict__ qbuf,
    const float* __restrict__ kbuf,
    const uint4* __restrict__ vbuf4,     // bf16 [64][NPOS], 8 per uint4
    const float* __restrict__ gamma,
    float* __restrict__ out)
{
    __shared__ floatx4 k_lds[256 * 2];   // [j][8] fp32 per key row (16B x2)
    __shared__ uint4   v_lds[64 * 33];   // [c][264] bf16, rows padded to 33 uint4

    const int t     = threadIdx.x;
    const int wave  = t >> 6;
    const int lane  = t & 63;
    const int m     = lane & 15;     // query within the wave's 16
    const int quad  = lane >> 4;     // 0..3
    const int kbase = quad * 8;      // this lane's key sub-slab inside 32

    const int i0 = blockIdx.x * 64;
    const int iq = i0 + wave * 16 + m;

    const floatx4 qa = *(const floatx4*)(qbuf + (size_t)iq * 8);
    const floatx4 qb = *(const floatx4*)(qbuf + (size_t)iq * 8 + 4);

    floatx4 acc[4];
#pragma unroll
    for (int ct = 0; ct < 4; ++ct) acc[ct] = (floatx4){0.f, 0.f, 0.f, 0.f};
    float den = 0.f;

#pragma unroll 1
    for (int j0 = 0; j0 < NPOS; j0 += 256) {
        __syncthreads();
        // stage k: thread t owns key row j0+t (32B)
        {
            const floatx4* kg = (const floatx4*)kbuf + (size_t)(j0 + t) * 2;
            k_lds[t * 2]     = kg[0];
            k_lds[t * 2 + 1] = kg[1];
        }
        // stage v: 64 rows x 32 uint4 (256 keys of bf16)
#pragma unroll
        for (int r = 0; r < 8; ++r) {
            const int idx  = t + r * 256;
            const int c    = idx >> 5;
            const int col8 = idx & 31;
            v_lds[c * 33 + col8] = vbuf4[(size_t)c * (NPOS / 8) + (j0 >> 3) + col8];
        }
        __syncthreads();

#pragma unroll
        for (int step = 0; step < 8; ++step) {
            // ---- scores + exp + A-frag (registers only) ----
            bf16x8 af;
#pragma unroll
            for (int jj = 0; jj < 8; ++jj) {
                const int row = step * 32 + kbase + jj;
                const floatx4 ka = k_lds[row * 2];
                const floatx4 kb = k_lds[row * 2 + 1];
                float s;
                s = qa.x * ka.x;
                s = fmaf(qa.y, ka.y, s);
                s = fmaf(qa.z, ka.z, s);
                s = fmaf(qa.w, ka.w, s);
                s = fmaf(qb.x, kb.x, s);
                s = fmaf(qb.y, kb.y, s);
                s = fmaf(qb.z, kb.z, s);
                s = fmaf(qb.w, kb.w, s);
                const float e = __expf(s);
                den += e;
                af[jj] = (short)(__builtin_bit_cast(unsigned int, e) >> 16);
            }
            // ---- PV via MFMA: 4 channel tiles of 16 ----
            const int coff = step * 4 + quad;   // uint4 column inside v_lds row
#pragma unroll
            for (int ct = 0; ct < 4; ++ct) {
                const int c = ct * 16 + m;      // B-frag n index = l&15
                const bf16x8 bfrag =
                    __builtin_bit_cast(bf16x8, v_lds[c * 33 + coff]);
                acc[ct] = __builtin_amdgcn_mfma_f32_16x16x32_bf16(
                    af, bfrag, acc[ct], 0, 0, 0);
            }
        }
    }

    // full denominator per query: lanes m, m+16, m+32, m+48 hold partials
    den += __shfl_xor(den, 16);
    den += __shfl_xor(den, 32);

    const float g = gamma[0];
    // C/D layout: col = l&15 (channel-within-tile), row = quad*4 + reg (query)
#pragma unroll
    for (int reg = 0; reg < 4; ++reg) {
        const float dv  = __shfl(den, quad * 4 + reg);  // den of query row
        const float inv = __builtin_amdgcn_rcpf(dv);
        const int i = i0 + wave * 16 + quad * 4 + reg;
#pragma unroll
        for (int ct = 0; ct < 4; ++ct) {
            const int c = ct * 16 + m;
            out[(size_t)c * NPOS + i] =
                fmaf(g, acc[ct][reg] * inv, x[(size_t)c * NPOS + i]);
        }
    }
}

// ---------------------------------------------------------------------------
extern "C" void kernel_launch(void* const* d_in, const int* in_sizes, int n_in,
                              void* d_out, int out_size, void* d_ws, size_t ws_size,
                              hipStream_t stream)
{
    (void)in_sizes; (void)n_in; (void)out_size; (void)ws_size;

    const float* x     = (const float*)d_in[0];
    const float* wq    = (const float*)d_in[1];
    const float* bq    = (const float*)d_in[2];
    const float* wk    = (const float*)d_in[3];
    const float* bk    = (const float*)d_in[4];
    const float* wv    = (const float*)d_in[5];
    const float* bv    = (const float*)d_in[6];
    const float* gamma = (const float*)d_in[7];
    float* out = (float*)d_out;

    char* ws = (char*)d_ws;
    float*          qbuf = (float*)(ws);                      // 16384*8*4  = 512 KB
    float*          kbuf = (float*)(ws + 524288);             // 512 KB
    unsigned short* vbuf = (unsigned short*)(ws + 1048576);   // 64*16384*2 = 2 MB

    proj_kernel<<<NPOS / 64, 64, 0, stream>>>(x, wq, bq, wk, bk, wv, bv,
                                              qbuf, kbuf, vbuf);
    attn_kernel<<<NPOS / 64, 256, 0, stream>>>(x, qbuf, kbuf,
                                               (const uint4*)vbuf, gamma, out);
}

// Round 4
// 277.292 us; speedup vs baseline: 2.0517x; 2.0517x over previous
//
#include <hip/hip_runtime.h>

#define NPOS 16384   // D*H*W = 16*32*32
#define CDIM 64
#define KSPLIT 4
#define KEYS_PER_BLK (NPOS / KSPLIT)   // 4096
#define CHUNK 128

typedef short bf16x8 __attribute__((ext_vector_type(8)));
typedef float floatx4 __attribute__((ext_vector_type(4)));

// ---------------------------------------------------------------------------
// Projection: q -> qbuf [n][8] fp32, k -> kswz (swizzled, see below),
// v -> vbuf bf16 [c][n].
// 256 threads: 64 positions x 4 waves; wave g handles v channels g*16..+15,
// wave 0 also does q, wave 1 also does k.
// kswz float layout: [chunk=n>>7][jj=n&7][col=(n&127)>>3][8]
// ---------------------------------------------------------------------------
__global__ __launch_bounds__(256) void proj_kernel(
    const float* __restrict__ x,
    const float* __restrict__ wq, const float* __restrict__ bq,
    const float* __restrict__ wk, const float* __restrict__ bk,
    const float* __restrict__ wv, const float* __restrict__ bv,
    float* __restrict__ qbuf, float* __restrict__ kswz,
    unsigned short* __restrict__ vbuf)
{
    const int t = threadIdx.x;
    const int n = blockIdx.x * 64 + (t & 63);
    const int g = t >> 6;   // wave id 0..3 (uniform per wave)

    float xr[64];
#pragma unroll
    for (int c = 0; c < 64; ++c) xr[c] = x[c * NPOS + n];

    if (g == 0) {
        float qv[8];
#pragma unroll
        for (int o = 0; o < 8; ++o) {
            const float* w = wq + o * 64;
            float s = bq[o];
#pragma unroll
            for (int c = 0; c < 64; ++c) s = fmaf(w[c], xr[c], s);
            qv[o] = s;
        }
        floatx4 a = {qv[0], qv[1], qv[2], qv[3]};
        floatx4 b = {qv[4], qv[5], qv[6], qv[7]};
        *(floatx4*)(qbuf + (size_t)n * 8)     = a;
        *(floatx4*)(qbuf + (size_t)n * 8 + 4) = b;
    } else if (g == 1) {
        float kv[8];
#pragma unroll
        for (int o = 0; o < 8; ++o) {
            const float* w = wk + o * 64;
            float s = bk[o];
#pragma unroll
            for (int c = 0; c < 64; ++c) s = fmaf(w[c], xr[c], s);
            kv[o] = s;
        }
        const size_t base = (size_t)(n >> 7) * 1024 + (size_t)(n & 7) * 128 +
                            (size_t)((n & 127) >> 3) * 8;
        floatx4 a = {kv[0], kv[1], kv[2], kv[3]};
        floatx4 b = {kv[4], kv[5], kv[6], kv[7]};
        *(floatx4*)(kswz + base)     = a;
        *(floatx4*)(kswz + base + 4) = b;
    }

    // v channels g*16 .. g*16+15
#pragma unroll
    for (int oo = 0; oo < 16; ++oo) {
        const int o = g * 16 + oo;
        const float* w = wv + o * 64;
        float s = bv[o];
#pragma unroll
        for (int c = 0; c < 64; ++c) s = fmaf(w[c], xr[c], s);
        vbuf[(size_t)o * NPOS + n] =
            (unsigned short)(__builtin_bit_cast(unsigned int, s) >> 16);
    }
}

// ---------------------------------------------------------------------------
// Attention partial kernel. Grid = 256 qblocks x KSPLIT key-quarters.
// Block: 256 thr = 4 waves x 16 queries; keys KEYS_PER_BLK in chunks of 128.
// Scores on VALU (K-dim=8), exp, bf16 A-frag in registers; PV via
// 4x v_mfma_f32_16x16x32_bf16. Partials accumulated to global via atomicAdd.
// ---------------------------------------------------------------------------
__global__ __launch_bounds__(256) void attn_kernel(
    const float* __restrict__ qbuf,
    const float* __restrict__ kswz,
    const uint4* __restrict__ vbuf4,     // bf16 [64][NPOS], 8 per uint4
    float* __restrict__ num,             // [64][NPOS] fp32, pre-zeroed
    float* __restrict__ den)             // [NPOS]     fp32, pre-zeroed
{
    __shared__ uint4 k_lds4[CHUNK * 2];      // 4 KB = 256 uint4 (full chunk)
    __shared__ uint4 v_lds[64 * 17];         // 17.4 KB, rows padded to 17

    float* k_lds = (float*)k_lds4;

    const int t    = threadIdx.x;
    const int wave = t >> 6;
    const int lane = t & 63;
    const int m    = lane & 15;
    const int quad = lane >> 4;

    const int qblk = blockIdx.x >> 2;
    const int kq   = blockIdx.x & 3;
    const int i0   = qblk * 64;
    const int jb   = kq * KEYS_PER_BLK;

    const int iq = i0 + wave * 16 + m;
    const floatx4 qa = *(const floatx4*)(qbuf + (size_t)iq * 8);
    const floatx4 qb = *(const floatx4*)(qbuf + (size_t)iq * 8 + 4);

    floatx4 acc[4];
#pragma unroll
    for (int ct = 0; ct < 4; ++ct) acc[ct] = (floatx4){0.f, 0.f, 0.f, 0.f};
    float den_r = 0.f;

#pragma unroll 1
    for (int jc = 0; jc < KEYS_PER_BLK; jc += CHUNK) {
        const int j0 = jb + jc;
        __syncthreads();
        // stage K: 4 KB = 256 uint4 (pre-swizzled); each thread one uint4
        k_lds4[t] = ((const uint4*)(kswz + (size_t)(j0 >> 7) * 1024))[t];
        // stage V: 64 rows x 16 uint4 (128 keys bf16)
#pragma unroll
        for (int r = 0; r < 4; ++r) {
            const int idx = t + r * 256;
            const int c   = idx >> 4;
            const int col = idx & 15;
            v_lds[c * 17 + col] = vbuf4[(size_t)c * (NPOS / 8) + (j0 >> 3) + col];
        }
        __syncthreads();

#pragma unroll
        for (int step = 0; step < CHUNK / 32; ++step) {
            bf16x8 af;
#pragma unroll
            for (int jj = 0; jj < 8; ++jj) {
                // swizzled: key (step*32 + quad*8 + jj) is at [jj][step*4+quad]
                const float* kr = k_lds + ((jj * 16) + (step * 4 + quad)) * 8;
                const floatx4 ka = *(const floatx4*)kr;
                const floatx4 kb = *(const floatx4*)(kr + 4);
                float s;
                s = qa.x * ka.x;
                s = fmaf(qa.y, ka.y, s);
                s = fmaf(qa.z, ka.z, s);
                s = fmaf(qa.w, ka.w, s);
                s = fmaf(qb.x, kb.x, s);
                s = fmaf(qb.y, kb.y, s);
                s = fmaf(qb.z, kb.z, s);
                s = fmaf(qb.w, kb.w, s);
                const float e = __expf(s);
                den_r += e;
                af[jj] = (short)(__builtin_bit_cast(unsigned int, e) >> 16);
            }
            const int coff = step * 4 + quad;
#pragma unroll
            for (int ct = 0; ct < 4; ++ct) {
                const bf16x8 bfrag =
                    __builtin_bit_cast(bf16x8, v_lds[(ct * 16 + m) * 17 + coff]);
                acc[ct] = __builtin_amdgcn_mfma_f32_16x16x32_bf16(
                    af, bfrag, acc[ct], 0, 0, 0);
            }
        }
    }

    // partial denominator per query over this key quarter
    den_r += __shfl_xor(den_r, 16);
    den_r += __shfl_xor(den_r, 32);
    if (quad == 0) atomicAdd(den + i0 + wave * 16 + m, den_r);

#pragma unroll
    for (int reg = 0; reg < 4; ++reg) {
        const int i = i0 + wave * 16 + quad * 4 + reg;
#pragma unroll
        for (int ct = 0; ct < 4; ++ct) {
            const int c = ct * 16 + m;
            atomicAdd(num + (size_t)c * NPOS + i, acc[ct][reg]);
        }
    }
}

// ---------------------------------------------------------------------------
__global__ __launch_bounds__(256) void finalize_kernel(
    const float* __restrict__ x,
    const float* __restrict__ num,
    const float* __restrict__ den,
    const float* __restrict__ gamma,
    float* __restrict__ out)
{
    const int idx = blockIdx.x * 256 + threadIdx.x;   // over 64*NPOS
    const int i   = idx & (NPOS - 1);
    const float g = gamma[0];
    out[idx] = fmaf(g, num[idx] * __builtin_amdgcn_rcpf(den[i]), x[idx]);
}

// ---------------------------------------------------------------------------
extern "C" void kernel_launch(void* const* d_in, const int* in_sizes, int n_in,
                              void* d_out, int out_size, void* d_ws, size_t ws_size,
                              hipStream_t stream)
{
    (void)in_sizes; (void)n_in; (void)out_size; (void)ws_size;

    const float* x     = (const float*)d_in[0];
    const float* wq    = (const float*)d_in[1];
    const float* bq    = (const float*)d_in[2];
    const float* wk    = (const float*)d_in[3];
    const float* bk    = (const float*)d_in[4];
    const float* wv    = (const float*)d_in[5];
    const float* bv    = (const float*)d_in[6];
    const float* gamma = (const float*)d_in[7];
    float* out = (float*)d_out;

    char* ws = (char*)d_ws;
    float*          num  = (float*)(ws);                        // 4 MB
    float*          den  = (float*)(ws + 4194304);              // 64 KB
    float*          qbuf = (float*)(ws + 4259840);              // 512 KB
    float*          kswz = (float*)(ws + 4784128);              // 512 KB
    unsigned short* vbuf = (unsigned short*)(ws + 5308416);     // 2 MB

    hipMemsetAsync(ws, 0, 4194304 + 65536, stream);             // num + den

    proj_kernel<<<NPOS / 64, 256, 0, stream>>>(x, wq, bq, wk, bk, wv, bv,
                                               qbuf, kswz, vbuf);
    attn_kernel<<<(NPOS / 64) * KSPLIT, 256, 0, stream>>>(
        qbuf, kswz, (const uint4*)vbuf, num, den);
    finalize_kernel<<<(CDIM * NPOS) / 256, 256, 0, stream>>>(x, num, den,
                                                             gamma, out);
}

// Round 5
// 233.625 us; speedup vs baseline: 2.4352x; 1.1869x over previous
//
#include <hip/hip_runtime.h>

#define NPOS 16384   // D*H*W
#define KSPLIT 8
#define KEYS_PER_BLK (NPOS / KSPLIT)   // 2048
#define CHUNK 128
#define LOG2E 1.4426950408889634f

typedef short bf16x8 __attribute__((ext_vector_type(8)));
typedef unsigned short u16x8 __attribute__((ext_vector_type(8)));
typedef float floatx16 __attribute__((ext_vector_type(16)));

static __device__ __forceinline__ unsigned short f2bf(float f) {
    return (unsigned short)(__builtin_bit_cast(unsigned int, f) >> 16);
}
static __device__ __forceinline__ float bf2f(unsigned short h) {
    return __builtin_bit_cast(float, (unsigned int)h << 16);
}

// ---------------------------------------------------------------------------
// Projection. 256 blocks x 1024 threads; 16 waves share 64 positions.
// wave g: v channels g*4..+3; waves 0-3: q outputs 2g,2g+1 (x LOG2E);
// waves 4-7: k outputs 2(g-4),2(g-4)+1. All outputs bf16.
// qb16/kb16: [n][8] bf16 (16B per position). vb16: [c][n] bf16.
// ---------------------------------------------------------------------------
__global__ __launch_bounds__(1024) void proj_kernel(
    const float* __restrict__ x,
    const float* __restrict__ wq, const float* __restrict__ bq,
    const float* __restrict__ wk, const float* __restrict__ bk,
    const float* __restrict__ wv, const float* __restrict__ bv,
    unsigned short* __restrict__ qb16, unsigned short* __restrict__ kb16,
    unsigned short* __restrict__ vb16)
{
    const int t = threadIdx.x;
    const int n = blockIdx.x * 64 + (t & 63);
    const int g = t >> 6;   // 0..15

    float xr[64];
#pragma unroll
    for (int c = 0; c < 64; ++c) xr[c] = x[c * NPOS + n];

    // v channels g*4 .. +3
#pragma unroll
    for (int oo = 0; oo < 4; ++oo) {
        const int o = g * 4 + oo;
        const float* w = wv + o * 64;
        float s = bv[o];
#pragma unroll
        for (int c = 0; c < 64; ++c) s = fmaf(w[c], xr[c], s);
        vb16[(size_t)o * NPOS + n] = f2bf(s);
    }

    if (g < 4) {            // q outputs 2g, 2g+1 (pre-scaled by log2(e))
        float sv[2];
#pragma unroll
        for (int oo = 0; oo < 2; ++oo) {
            const int o = 2 * g + oo;
            const float* w = wq + o * 64;
            float s = bq[o];
#pragma unroll
            for (int c = 0; c < 64; ++c) s = fmaf(w[c], xr[c], s);
            sv[oo] = s * LOG2E;
        }
        const unsigned int u = (unsigned int)f2bf(sv[0]) |
                               ((unsigned int)f2bf(sv[1]) << 16);
        *(unsigned int*)(qb16 + (size_t)n * 8 + 2 * g) = u;
    } else if (g < 8) {     // k outputs
        const int gg = g - 4;
        float sv[2];
#pragma unroll
        for (int oo = 0; oo < 2; ++oo) {
            const int o = 2 * gg + oo;
            const float* w = wk + o * 64;
            float s = bk[o];
#pragma unroll
            for (int c = 0; c < 64; ++c) s = fmaf(w[c], xr[c], s);
            sv[oo] = s;
        }
        const unsigned int u = (unsigned int)f2bf(sv[0]) |
                               ((unsigned int)f2bf(sv[1]) << 16);
        *(unsigned int*)(kb16 + (size_t)n * 8 + 2 * gg) = u;
    }
}

// ---------------------------------------------------------------------------
// Attention partials. Grid = 256 qblocks x 8 kq = 2048 blocks, 256 threads.
// Wave (qhalf=wave>>1, khalf=wave&1): 32 queries x 64-key half of each chunk.
// Scores: one v_mfma_f32_32x32x16_bf16 per 32x32 tile (channels zero-padded
// to K=16 via half-frag zeroing). exp2 (q pre-scaled), bf16 pack -> wave-
// private p_lds -> A-frag b128 -> PV via 4 MFMAs per tile (2 ksteps x 2 ch
// halves). Epilogue: LDS transpose -> coalesced bf16 partial stores; den via
// shared-mem reduction (no global atomics, no memset).
// ---------------------------------------------------------------------------
__global__ __launch_bounds__(256, 4) void attn_kernel(
    const uint4* __restrict__ qb4,   // [n] 8 bf16
    const uint4* __restrict__ kb4,   // [n] 8 bf16
    const uint4* __restrict__ vb4,   // [c][NPOS/8] 8 bf16 each
    unsigned short* __restrict__ nump,  // [8][64][NPOS] bf16
    float* __restrict__ denp)           // [8][NPOS] fp32
{
    __shared__ __align__(16) char smem[29952];
    uint4*          k_lds = (uint4*)smem;                      // 2048 B
    uint4*          v_lds = (uint4*)(smem + 2048);             // 64 x 17 uint4
    unsigned short* p16   = (unsigned short*)(smem + 19456);   // 4 x 32 x 40
    float*          den_s = (float*)(smem + 29696);            // 64 f32
    unsigned short* o16   = (unsigned short*)smem;             // epilogue alias

    const int t     = threadIdx.x;
    const int wave  = t >> 6;
    const int lane  = t & 63;
    const int m     = lane & 31;
    const int half  = lane >> 5;
    const int qhalf = wave >> 1;
    const int khalf = wave & 1;

    const int qblk = blockIdx.x >> 3;
    const int kq   = blockIdx.x & 7;
    const int i0   = qblk * 64;
    const int jb   = kq * KEYS_PER_BLK;

    if (t < 64) den_s[t] = 0.f;

    // Q A-frag: A[m=query][k=half*8+j]; channels 0..7 live in half 0 only.
    uint4 qa4 = qb4[i0 + qhalf * 32 + m];
    if (half) qa4 = make_uint4(0, 0, 0, 0);
    const bf16x8 aq = __builtin_bit_cast(bf16x8, qa4);

    floatx16 accA = {};   // channels 0..31
    floatx16 accB = {};   // channels 32..63
    float dacc[16];
#pragma unroll
    for (int r = 0; r < 16; ++r) dacc[r] = 0.f;

    const int pbase = wave * 1280;   // ushorts; rows stride 40 (80 B, 16-aligned)

#pragma unroll 1
    for (int jc = 0; jc < KEYS_PER_BLK; jc += CHUNK) {
        const int j0 = jb + jc;
        __syncthreads();
        if (t < 128) k_lds[t] = kb4[j0 + t];
#pragma unroll
        for (int r = 0; r < 4; ++r) {
            const int idx = t + r * 256;
            const int c   = idx >> 4;
            const int col = idx & 15;
            v_lds[c * 17 + col] = vb4[(size_t)c * (NPOS / 8) + (j0 >> 3) + col];
        }
        __syncthreads();

#pragma unroll
        for (int st = 0; st < 2; ++st) {
            const int kb = khalf * 64 + st * 32;   // tile's 32 keys in chunk
            // K B-frag: B[k=half*8+j][n=key]; channels live in half 0 only.
            uint4 b4 = k_lds[kb + m];
            if (half) b4 = make_uint4(0, 0, 0, 0);
            const floatx16 s = __builtin_amdgcn_mfma_f32_32x32x16_bf16(
                aq, __builtin_bit_cast(bf16x8, b4), (floatx16){}, 0, 0, 0);
            // exp2 + den + pack to p_lds (C layout: col=key=m, row below)
#pragma unroll
            for (int r = 0; r < 16; ++r) {
                const float e = exp2f(s[r]);
                dacc[r] += e;
                const int row = (r & 3) + 8 * (r >> 2) + 4 * half;
                p16[pbase + row * 40 + m] = f2bf(e);
            }
            // PV: A[m=query][k=half*8+j] from p_lds; B from v_lds
#pragma unroll
            for (int ks2 = 0; ks2 < 2; ++ks2) {
                const bf16x8 af = *(const bf16x8*)(p16 + pbase + m * 40 +
                                                   ks2 * 16 + half * 8);
                const int col = khalf * 8 + st * 4 + ks2 * 2 + half;
                const bf16x8 v0 =
                    __builtin_bit_cast(bf16x8, v_lds[m * 17 + col]);
                const bf16x8 v1 =
                    __builtin_bit_cast(bf16x8, v_lds[(32 + m) * 17 + col]);
                accA = __builtin_amdgcn_mfma_f32_32x32x16_bf16(af, v0, accA,
                                                               0, 0, 0);
                accB = __builtin_amdgcn_mfma_f32_32x32x16_bf16(af, v1, accB,
                                                               0, 0, 0);
            }
        }
    }

    // den: reduce across the 32 lanes of each half (key-columns)
#pragma unroll
    for (int r = 0; r < 16; ++r) {
        float d = dacc[r];
        d += __shfl_xor(d, 1);
        d += __shfl_xor(d, 2);
        d += __shfl_xor(d, 4);
        d += __shfl_xor(d, 8);
        d += __shfl_xor(d, 16);
        dacc[r] = d;
    }

    __syncthreads();   // main-loop LDS traffic done; safe to alias o16

    // epilogue transpose: o16[wave][32 q][66] (c = chh*32 + m)
    const int obase = wave * 2112;
#pragma unroll
    for (int r = 0; r < 16; ++r) {
        const int row = (r & 3) + 8 * (r >> 2) + 4 * half;
        o16[obase + row * 66 + m]      = f2bf(accA[r]);
        o16[obase + row * 66 + 32 + m] = f2bf(accB[r]);
    }
    if (m == 0) {
#pragma unroll
        for (int r = 0; r < 16; ++r) {
            const int row = (r & 3) + 8 * (r >> 2) + 4 * half;
            atomicAdd(den_s + qhalf * 32 + row, dacc[r]);
        }
    }
    __syncthreads();

    // coalesced partial stores: thread t -> channel c = t>>2, i-quarter t&3
    {
        const int c   = t >> 2;
        const int qtr = t & 3;
        u16x8 h0, h1;
#pragma unroll
        for (int j = 0; j < 16; ++j) {
            const int q  = qtr * 16 + j;
            const int qh = q >> 5;
            const int ql = q & 31;
            const float v = bf2f(o16[(qh * 2) * 2112 + ql * 66 + c]) +
                            bf2f(o16[(qh * 2 + 1) * 2112 + ql * 66 + c]);
            if (j < 8) h0[j] = f2bf(v);
            else       h1[j - 8] = f2bf(v);
        }
        unsigned short* dst =
            nump + (((size_t)(kq * 64 + c)) << 14) + i0 + qtr * 16;
        ((uint4*)dst)[0] = __builtin_bit_cast(uint4, h0);
        ((uint4*)dst)[1] = __builtin_bit_cast(uint4, h1);
        if (t < 64) denp[kq * NPOS + i0 + t] = den_s[t];
    }
}

// ---------------------------------------------------------------------------
__global__ __launch_bounds__(256) void finalize_kernel(
    const float* __restrict__ x,
    const unsigned short* __restrict__ nump,
    const float* __restrict__ denp,
    const float* __restrict__ gamma,
    float* __restrict__ out)
{
    const int idx = blockIdx.x * 256 + threadIdx.x;   // over 64*NPOS
    const int n   = idx & (NPOS - 1);
    const int c   = idx >> 14;
    float ns = 0.f, ds = 0.f;
#pragma unroll
    for (int kq = 0; kq < 8; ++kq) {
        ns += bf2f(nump[(((size_t)(kq * 64 + c)) << 14) + n]);
        ds += denp[kq * NPOS + n];
    }
    out[idx] = fmaf(gamma[0], ns * __builtin_amdgcn_rcpf(ds), x[idx]);
}

// ---------------------------------------------------------------------------
extern "C" void kernel_launch(void* const* d_in, const int* in_sizes, int n_in,
                              void* d_out, int out_size, void* d_ws, size_t ws_size,
                              hipStream_t stream)
{
    (void)in_sizes; (void)n_in; (void)out_size; (void)ws_size;

    const float* x     = (const float*)d_in[0];
    const float* wq    = (const float*)d_in[1];
    const float* bq    = (const float*)d_in[2];
    const float* wk    = (const float*)d_in[3];
    const float* bk    = (const float*)d_in[4];
    const float* wv    = (const float*)d_in[5];
    const float* bv    = (const float*)d_in[6];
    const float* gamma = (const float*)d_in[7];
    float* out = (float*)d_out;

    char* ws = (char*)d_ws;
    unsigned short* qb16 = (unsigned short*)(ws);               // 256 KB
    unsigned short* kb16 = (unsigned short*)(ws + 262144);      // 256 KB
    unsigned short* vb16 = (unsigned short*)(ws + 524288);      // 2 MB
    unsigned short* nump = (unsigned short*)(ws + 2621440);     // 16 MB bf16
    float*          denp = (float*)(ws + 19398656);             // 512 KB

    proj_kernel<<<NPOS / 64, 1024, 0, stream>>>(x, wq, bq, wk, bk, wv, bv,
                                                qb16, kb16, vb16);
    attn_kernel<<<(NPOS / 64) * KSPLIT, 256, 0, stream>>>(
        (const uint4*)qb16, (const uint4*)kb16, (const uint4*)vb16,
        nump, denp);
    finalize_kernel<<<(64 * NPOS) / 256, 256, 0, stream>>>(x, nump, denp,
                                                           gamma, out);
}

// Round 6
// 161.347 us; speedup vs baseline: 3.5261x; 1.4480x over previous
//
#include <hip/hip_runtime.h>

#define NPOS 16384   // D*H*W
#define KSPLIT 8
#define KEYS_PER_BLK (NPOS / KSPLIT)   // 2048
#define CHUNK 128
#define LOG2E 1.4426950408889634f

typedef short bf16x8 __attribute__((ext_vector_type(8)));
typedef unsigned short u16x8 __attribute__((ext_vector_type(8)));
typedef float floatx16 __attribute__((ext_vector_type(16)));

static __device__ __forceinline__ unsigned short f2bf(float f) {
    return (unsigned short)(__builtin_bit_cast(unsigned int, f) >> 16);
}
static __device__ __forceinline__ float bf2f(unsigned short h) {
    return __builtin_bit_cast(float, (unsigned int)h << 16);
}

#if __has_builtin(__builtin_amdgcn_exp2f)
#define EXP2(v) __builtin_amdgcn_exp2f(v)
#else
#define EXP2(v) __expf((v) * 0.6931471805599453f)
#endif

// pack hi16(a_even)|hi16(a_odd) -> one VGPR holding 2 bf16 (even in low half)
static __device__ __forceinline__ unsigned int pk_bf16(float e_even, float e_odd) {
    return __builtin_amdgcn_perm(__builtin_bit_cast(unsigned int, e_odd),
                                 __builtin_bit_cast(unsigned int, e_even),
                                 0x07060302u);
}

// ---------------------------------------------------------------------------
// Projection. Grid (64, 5), block 256. Thread = one position n x one group g.
// g==0: q[0..7] (prescaled by log2e) + k[0..7] -> qb16/kb16 [n][8] bf16.
// g>=1: v channels (g-1)*16 .. +15 -> vb16 [c][n] bf16.
// 16 accumulators/thread, NO per-thread x array (previous version spilled).
// ---------------------------------------------------------------------------
__global__ __launch_bounds__(256) void proj_kernel(
    const float* __restrict__ x,
    const float* __restrict__ wq, const float* __restrict__ bq,
    const float* __restrict__ wk, const float* __restrict__ bk,
    const float* __restrict__ wv, const float* __restrict__ bv,
    unsigned short* __restrict__ qb16, unsigned short* __restrict__ kb16,
    unsigned short* __restrict__ vb16)
{
    const int t = threadIdx.x;
    const int n = blockIdx.x * 256 + t;
    const int g = blockIdx.y;

    float acc[16];
    if (g == 0) {
#pragma unroll
        for (int oo = 0; oo < 8; ++oo) { acc[oo] = bq[oo]; acc[8 + oo] = bk[oo]; }
#pragma unroll 16
        for (int c = 0; c < 64; ++c) {
            const float xv = x[c * NPOS + n];
#pragma unroll
            for (int oo = 0; oo < 8; ++oo) {
                acc[oo]     = fmaf(wq[oo * 64 + c], xv, acc[oo]);
                acc[8 + oo] = fmaf(wk[oo * 64 + c], xv, acc[8 + oo]);
            }
        }
        u16x8 qp, kp;
#pragma unroll
        for (int j = 0; j < 8; ++j) {
            qp[j] = f2bf(acc[j] * LOG2E);
            kp[j] = f2bf(acc[8 + j]);
        }
        ((uint4*)qb16)[n] = __builtin_bit_cast(uint4, qp);
        ((uint4*)kb16)[n] = __builtin_bit_cast(uint4, kp);
    } else {
        const int o0 = (g - 1) * 16;
#pragma unroll
        for (int oo = 0; oo < 16; ++oo) acc[oo] = bv[o0 + oo];
#pragma unroll 16
        for (int c = 0; c < 64; ++c) {
            const float xv = x[c * NPOS + n];
#pragma unroll
            for (int oo = 0; oo < 16; ++oo)
                acc[oo] = fmaf(wv[(o0 + oo) * 64 + c], xv, acc[oo]);
        }
#pragma unroll
        for (int oo = 0; oo < 16; ++oo)
            vb16[(size_t)(o0 + oo) * NPOS + n] = f2bf(acc[oo]);
    }
}

// ---------------------------------------------------------------------------
// Attention partials. Grid = 256 qblocks x 8 kq, 256 threads (4 waves).
// Wave (qhalf, khalf): 32 queries x 64-key half of each 128-key chunk.
//
// Scores computed TRANSPOSED: T = K*Q^T via mfma_32x32x16_bf16 with
// A[m=key][k=chan] (half1 zero via zeroed LDS slot), B[k=chan][n=query].
// C/D layout => lane(l&31)=query, rows=keys (r&3)+8*(r>>2)+4*half. So each
// lane holds 16 key-scores of ITS OWN query: exactly the PV A-operand data.
// exp2 -> pack bf16 pairs (v_perm) -> half-swap via shfl_xor(32):
//   half0 P0..P7 = keys (0,1)(2,3)(8,9)(10,11)(16,17)(18,19)(24,25)(26,27)
//   half1 P0..P7 = keys (4,5)(6,7)(12,13)(14,15)(20,21)(22,23)(28,29)(30,31)
//   frag f (keys f*16..+15): half0 needs [P(4f),P(4f+1),theirP(4f),theirP(4f+1)]
//                            half1 needs [theirP(4f+2),theirP(4f+3),P(4f+2),P(4f+3)]
// PV: A=P-frag, B=V rows from LDS ([c][key] padded); D: lane=channel, rows=query.
// ---------------------------------------------------------------------------
__global__ __launch_bounds__(256, 4) void attn_kernel(
    const uint4* __restrict__ qb4,   // [n] 8 bf16 (prescaled log2e)
    const uint4* __restrict__ kb4,   // [n] 8 bf16
    const uint4* __restrict__ vb4,   // [c][NPOS/8]
    unsigned short* __restrict__ nump,  // [8][64][NPOS] bf16
    float* __restrict__ denp)           // [8][NPOS] fp32
{
    __shared__ __align__(16) char smem[19776];
    uint4*          k_lds = (uint4*)smem;                    // 129 used (+pad)
    uint4*          v_lds = (uint4*)(smem + 2112);           // 64 x 17
    float*          den_s = (float*)(smem + 19520);          // 64 f32
    unsigned short* o16   = (unsigned short*)smem;           // epilogue alias

    const int t     = threadIdx.x;
    const int wave  = t >> 6;
    const int lane  = t & 63;
    const int m     = lane & 31;
    const int half  = lane >> 5;
    const int qhalf = wave >> 1;
    const int khalf = wave & 1;

    const int qblk = blockIdx.x >> 3;
    const int kq   = blockIdx.x & 7;
    const int i0   = qblk * 64;
    const int jb   = kq * KEYS_PER_BLK;

    if (t < 64) den_s[t] = 0.f;
    if (t == 0) k_lds[128] = make_uint4(0, 0, 0, 0);   // zero slot for half1 A

    // B operand (queries): lane m = query qhalf*32+m, regs = channels, half1 zero
    uint4 qa4 = (half == 0) ? qb4[i0 + qhalf * 32 + m] : make_uint4(0, 0, 0, 0);
    const bf16x8 bqf = __builtin_bit_cast(bf16x8, qa4);

    floatx16 accA = {};   // channels 0..31
    floatx16 accB = {};   // channels 32..63
    float dacc = 0.f;

#pragma unroll 1
    for (int jc = 0; jc < KEYS_PER_BLK; jc += CHUNK) {
        const int j0 = jb + jc;
        __syncthreads();
        if (t < 128) k_lds[t] = kb4[j0 + t];
#pragma unroll
        for (int r = 0; r < 4; ++r) {
            const int idx = t + r * 256;
            const int c   = idx >> 4;
            const int col = idx & 15;
            v_lds[c * 17 + col] = vb4[(size_t)c * (NPOS / 8) + (j0 >> 3) + col];
        }
        __syncthreads();

#pragma unroll
        for (int st = 0; st < 2; ++st) {
            const int kb   = khalf * 64 + st * 32;
            const int kidx = half ? 128 : (kb + m);
            const bf16x8 ak = __builtin_bit_cast(bf16x8, k_lds[kidx]);
            const floatx16 s = __builtin_amdgcn_mfma_f32_32x32x16_bf16(
                ak, bqf, (floatx16){}, 0, 0, 0);

            float e[16];
#pragma unroll
            for (int r = 0; r < 16; ++r) {
                e[r] = EXP2(s[r]);
                dacc += e[r];
            }
            unsigned int P[8];
#pragma unroll
            for (int p = 0; p < 8; ++p) P[p] = pk_bf16(e[2 * p], e[2 * p + 1]);

#pragma unroll
            for (int f = 0; f < 2; ++f) {
                const unsigned int s0 = half ? P[4 * f + 0] : P[4 * f + 2];
                const unsigned int s1 = half ? P[4 * f + 1] : P[4 * f + 3];
                const unsigned int r0 = __shfl_xor(s0, 32);
                const unsigned int r1 = __shfl_xor(s1, 32);
                uint4 afu;
                afu.x = half ? r0 : P[4 * f + 0];
                afu.y = half ? r1 : P[4 * f + 1];
                afu.z = half ? P[4 * f + 2] : r0;
                afu.w = half ? P[4 * f + 3] : r1;
                const bf16x8 af = __builtin_bit_cast(bf16x8, afu);

                const int col = khalf * 8 + st * 4 + f * 2 + half;
                const bf16x8 v0 =
                    __builtin_bit_cast(bf16x8, v_lds[m * 17 + col]);
                const bf16x8 v1 =
                    __builtin_bit_cast(bf16x8, v_lds[(32 + m) * 17 + col]);
                accA = __builtin_amdgcn_mfma_f32_32x32x16_bf16(af, v0, accA,
                                                               0, 0, 0);
                accB = __builtin_amdgcn_mfma_f32_32x32x16_bf16(af, v1, accB,
                                                               0, 0, 0);
            }
        }
    }

    // den: lane's dacc covers its query's keys in this half; combine halves
    {
        const float d = dacc + __shfl_xor(dacc, 32);
        if (half == 0) atomicAdd(den_s + qhalf * 32 + m, d);
    }

    __syncthreads();   // main-loop LDS done; safe to alias o16

    // epilogue transpose: o16[wave][32 q][66] (channel c = chhalf*32 + m)
    const int obase = wave * 2112;
#pragma unroll
    for (int r = 0; r < 16; ++r) {
        const int row = (r & 3) + 8 * (r >> 2) + 4 * half;
        o16[obase + row * 66 + m]      = f2bf(accA[r]);
        o16[obase + row * 66 + 32 + m] = f2bf(accB[r]);
    }
    __syncthreads();

    // coalesced partial stores: thread t -> channel c = t>>2, i-quarter t&3
    {
        const int c   = t >> 2;
        const int qtr = t & 3;
        u16x8 h0, h1;
#pragma unroll
        for (int j = 0; j < 16; ++j) {
            const int q  = qtr * 16 + j;
            const int qh = q >> 5;
            const int ql = q & 31;
            const float v = bf2f(o16[(qh * 2) * 2112 + ql * 66 + c]) +
                            bf2f(o16[(qh * 2 + 1) * 2112 + ql * 66 + c]);
            if (j < 8) h0[j] = f2bf(v);
            else       h1[j - 8] = f2bf(v);
        }
        unsigned short* dst =
            nump + (((size_t)(kq * 64 + c)) << 14) + i0 + qtr * 16;
        ((uint4*)dst)[0] = __builtin_bit_cast(uint4, h0);
        ((uint4*)dst)[1] = __builtin_bit_cast(uint4, h1);
        if (t < 64) denp[kq * NPOS + i0 + t] = den_s[t];
    }
}

// ---------------------------------------------------------------------------
__global__ __launch_bounds__(256) void finalize_kernel(
    const float* __restrict__ x,
    const unsigned short* __restrict__ nump,
    const float* __restrict__ denp,
    const float* __restrict__ gamma,
    float* __restrict__ out)
{
    const int idx = blockIdx.x * 256 + threadIdx.x;   // over 64*NPOS
    const int n   = idx & (NPOS - 1);
    const int c   = idx >> 14;
    float ns = 0.f, ds = 0.f;
#pragma unroll
    for (int kq = 0; kq < 8; ++kq) {
        ns += bf2f(nump[(((size_t)(kq * 64 + c)) << 14) + n]);
        ds += denp[kq * NPOS + n];
    }
    out[idx] = fmaf(gamma[0], ns * __builtin_amdgcn_rcpf(ds), x[idx]);
}

// ---------------------------------------------------------------------------
extern "C" void kernel_launch(void* const* d_in, const int* in_sizes, int n_in,
                              void* d_out, int out_size, void* d_ws, size_t ws_size,
                              hipStream_t stream)
{
    (void)in_sizes; (void)n_in; (void)out_size; (void)ws_size;

    const float* x     = (const float*)d_in[0];
    const float* wq    = (const float*)d_in[1];
    const float* bq    = (const float*)d_in[2];
    const float* wk    = (const float*)d_in[3];
    const float* bk    = (const float*)d_in[4];
    const float* wv    = (const float*)d_in[5];
    const float* bv    = (const float*)d_in[6];
    const float* gamma = (const float*)d_in[7];
    float* out = (float*)d_out;

    char* ws = (char*)d_ws;
    unsigned short* qb16 = (unsigned short*)(ws);               // 256 KB
    unsigned short* kb16 = (unsigned short*)(ws + 262144);      // 256 KB
    unsigned short* vb16 = (unsigned short*)(ws + 524288);      // 2 MB
    unsigned short* nump = (unsigned short*)(ws + 2621440);     // 16 MB bf16
    float*          denp = (float*)(ws + 19398656);             // 512 KB

    proj_kernel<<<dim3(NPOS / 256, 5), 256, 0, stream>>>(
        x, wq, bq, wk, bk, wv, bv, qb16, kb16, vb16);
    attn_kernel<<<(NPOS / 64) * KSPLIT, 256, 0, stream>>>(
        (const uint4*)qb16, (const uint4*)kb16, (const uint4*)vb16,
        nump, denp);
    finalize_kernel<<<(64 * NPOS) / 256, 256, 0, stream>>>(x, nump, denp,
                                                           gamma, out);
}

// Round 7
// 157.159 us; speedup vs baseline: 3.6201x; 1.0267x over previous
//
#include <hip/hip_runtime.h>

#define NPOS 16384   // D*H*W
#define KSPLIT 8
#define KEYS_PER_BLK (NPOS / KSPLIT)   // 2048
#define CHUNK 128
#define LOG2E 1.4426950408889634f

typedef short bf16x8 __attribute__((ext_vector_type(8)));
typedef unsigned short u16x8 __attribute__((ext_vector_type(8)));
typedef float floatx16 __attribute__((ext_vector_type(16)));

static __device__ __forceinline__ unsigned short f2bf(float f) {
    return (unsigned short)(__builtin_bit_cast(unsigned int, f) >> 16);
}
static __device__ __forceinline__ float bf2f(unsigned short h) {
    return __builtin_bit_cast(float, (unsigned int)h << 16);
}

// raw v_exp_f32 (2^x), no libm fixups
#if __has_builtin(__builtin_amdgcn_exp2f)
static __device__ __forceinline__ float exp2_fast(float x) {
    return __builtin_amdgcn_exp2f(x);
}
#else
static __device__ __forceinline__ float exp2_fast(float x) {
    float r;
    asm("v_exp_f32 %0, %1" : "=v"(r) : "v"(x));
    return r;
}
#endif

// pack hi16(a_even)|hi16(a_odd) -> one VGPR holding 2 bf16 (even in low half)
static __device__ __forceinline__ unsigned int pk_bf16(float e_even, float e_odd) {
    return __builtin_amdgcn_perm(__builtin_bit_cast(unsigned int, e_odd),
                                 __builtin_bit_cast(unsigned int, e_even),
                                 0x07060302u);
}

// ---------------------------------------------------------------------------
// Projection. Grid (64, 5), block 256. Thread = one position n x one group g.
// g==0: q[0..7] (prescaled by log2e) + k[0..7] -> qb16/kb16 [n][8] bf16.
// g>=1: v channels (g-1)*16 .. +15 -> vb16 [c][sigma(n)] bf16, where
// sigma swaps the middle two 4-key nibbles of each 16 (n^12 when (n&12) in
// {4,8}). This makes the PV A-fragment equal each lane's own score registers
// (see attn_kernel header) -- no cross-lane exchange needed.
// ---------------------------------------------------------------------------
__global__ __launch_bounds__(256) void proj_kernel(
    const float* __restrict__ x,
    const float* __restrict__ wq, const float* __restrict__ bq,
    const float* __restrict__ wk, const float* __restrict__ bk,
    const float* __restrict__ wv, const float* __restrict__ bv,
    unsigned short* __restrict__ qb16, unsigned short* __restrict__ kb16,
    unsigned short* __restrict__ vb16)
{
    const int t = threadIdx.x;
    const int n = blockIdx.x * 256 + t;
    const int g = blockIdx.y;

    float acc[16];
    if (g == 0) {
#pragma unroll
        for (int oo = 0; oo < 8; ++oo) { acc[oo] = bq[oo]; acc[8 + oo] = bk[oo]; }
#pragma unroll 16
        for (int c = 0; c < 64; ++c) {
            const float xv = x[c * NPOS + n];
#pragma unroll
            for (int oo = 0; oo < 8; ++oo) {
                acc[oo]     = fmaf(wq[oo * 64 + c], xv, acc[oo]);
                acc[8 + oo] = fmaf(wk[oo * 64 + c], xv, acc[8 + oo]);
            }
        }
        u16x8 qp, kp;
#pragma unroll
        for (int j = 0; j < 8; ++j) {
            qp[j] = f2bf(acc[j] * LOG2E);
            kp[j] = f2bf(acc[8 + j]);
        }
        ((uint4*)qb16)[n] = __builtin_bit_cast(uint4, qp);
        ((uint4*)kb16)[n] = __builtin_bit_cast(uint4, kp);
    } else {
        const int o0 = (g - 1) * 16;
#pragma unroll
        for (int oo = 0; oo < 16; ++oo) acc[oo] = bv[o0 + oo];
#pragma unroll 16
        for (int c = 0; c < 64; ++c) {
            const float xv = x[c * NPOS + n];
#pragma unroll
            for (int oo = 0; oo < 16; ++oo)
                acc[oo] = fmaf(wv[(o0 + oo) * 64 + c], xv, acc[oo]);
        }
        const int w12 = n & 12;
        const int np  = (w12 == 4 || w12 == 8) ? (n ^ 12) : n;  // sigma(n)
#pragma unroll
        for (int oo = 0; oo < 16; ++oo)
            vb16[(size_t)(o0 + oo) * NPOS + np] = f2bf(acc[oo]);
    }
}

// ---------------------------------------------------------------------------
// Attention partials. Grid = 256 qblocks x 8 kq, 256 threads (4 waves).
// Wave (qhalf, khalf): 32 queries x 64-key half of each 128-key chunk.
//
// Scores TRANSPOSED: T = K*Q^T via mfma_32x32x16_bf16, A[m=key][k=chan]
// (half1 zero via zeroed LDS slot), B[k=chan][n=query]. C/D: lane(l&31)=query,
// row r = key (r&3)+8*(r>>2)+4*half (natural order). With V stored in sigma
// key order, PV A-frag f is exactly rows 8f..8f+7 = regs P[4f..4f+3]:
//   sigma positions f*16+half*8+j <-> this lane's rows 8f+j.  No exchange.
// PV: A=P, B=V rows from LDS ([c][sigma-key] padded); D: lane=channel,
// rows=query.
// ---------------------------------------------------------------------------
__global__ __launch_bounds__(256, 4) void attn_kernel(
    const uint4* __restrict__ qb4,   // [n] 8 bf16 (prescaled log2e)
    const uint4* __restrict__ kb4,   // [n] 8 bf16, natural order
    const uint4* __restrict__ vb4,   // [c][NPOS/8], sigma key order
    unsigned short* __restrict__ nump,  // [8][64][NPOS] bf16
    float* __restrict__ denp)           // [8][NPOS] fp32
{
    __shared__ __align__(16) char smem[19776];
    uint4*          k_lds = (uint4*)smem;                    // 129 used
    uint4*          v_lds = (uint4*)(smem + 2112);           // 64 x 17
    float*          den_s = (float*)(smem + 19520);          // 64 f32
    unsigned short* o16   = (unsigned short*)smem;           // epilogue alias

    const int t     = threadIdx.x;
    const int wave  = t >> 6;
    const int lane  = t & 63;
    const int m     = lane & 31;
    const int half  = lane >> 5;
    const int qhalf = wave >> 1;
    const int khalf = wave & 1;

    const int qblk = blockIdx.x >> 3;
    const int kq   = blockIdx.x & 7;
    const int i0   = qblk * 64;
    const int jb   = kq * KEYS_PER_BLK;

    if (t < 64) den_s[t] = 0.f;
    if (t == 0) k_lds[128] = make_uint4(0, 0, 0, 0);   // zero slot (half1 A)

    // B operand (queries): lane m = query qhalf*32+m, regs = chans, half1 zero
    uint4 qa4 = (half == 0) ? qb4[i0 + qhalf * 32 + m] : make_uint4(0, 0, 0, 0);
    const bf16x8 bqf = __builtin_bit_cast(bf16x8, qa4);

    floatx16 accA = {};   // channels 0..31
    floatx16 accB = {};   // channels 32..63
    float dacc = 0.f;

#pragma unroll 1
    for (int jc = 0; jc < KEYS_PER_BLK; jc += CHUNK) {
        const int j0 = jb + jc;
        __syncthreads();
        if (t < 128) k_lds[t] = kb4[j0 + t];
#pragma unroll
        for (int r = 0; r < 4; ++r) {
            const int idx = t + r * 256;
            const int c   = idx >> 4;
            const int col = idx & 15;
            v_lds[c * 17 + col] = vb4[(size_t)c * (NPOS / 8) + (j0 >> 3) + col];
        }
        __syncthreads();

#pragma unroll
        for (int st = 0; st < 2; ++st) {
            const int kb   = khalf * 64 + st * 32;
            const int kidx = half ? 128 : (kb + m);
            const bf16x8 ak = __builtin_bit_cast(bf16x8, k_lds[kidx]);
            const floatx16 s = __builtin_amdgcn_mfma_f32_32x32x16_bf16(
                ak, bqf, (floatx16){}, 0, 0, 0);

            float e[16];
#pragma unroll
            for (int r = 0; r < 16; ++r) {
                e[r] = exp2_fast(s[r]);
                dacc += e[r];
            }
            unsigned int P[8];
#pragma unroll
            for (int p = 0; p < 8; ++p) P[p] = pk_bf16(e[2 * p], e[2 * p + 1]);

#pragma unroll
            for (int f = 0; f < 2; ++f) {
                uint4 afu;
                afu.x = P[4 * f + 0];
                afu.y = P[4 * f + 1];
                afu.z = P[4 * f + 2];
                afu.w = P[4 * f + 3];
                const bf16x8 af = __builtin_bit_cast(bf16x8, afu);

                const int col = khalf * 8 + st * 4 + f * 2 + half;
                const bf16x8 v0 =
                    __builtin_bit_cast(bf16x8, v_lds[m * 17 + col]);
                const bf16x8 v1 =
                    __builtin_bit_cast(bf16x8, v_lds[(32 + m) * 17 + col]);
                accA = __builtin_amdgcn_mfma_f32_32x32x16_bf16(af, v0, accA,
                                                               0, 0, 0);
                accB = __builtin_amdgcn_mfma_f32_32x32x16_bf16(af, v1, accB,
                                                               0, 0, 0);
            }
        }
    }

    // den: lane's dacc covers its query's keys in this half; combine halves
    {
        const float d = dacc + __shfl_xor(dacc, 32);
        if (half == 0) atomicAdd(den_s + qhalf * 32 + m, d);
    }

    __syncthreads();   // main-loop LDS done; safe to alias o16

    // epilogue transpose: o16[wave][32 q][66] (channel c = chhalf*32 + m)
    const int obase = wave * 2112;
#pragma unroll
    for (int r = 0; r < 16; ++r) {
        const int row = (r & 3) + 8 * (r >> 2) + 4 * half;
        o16[obase + row * 66 + m]      = f2bf(accA[r]);
        o16[obase + row * 66 + 32 + m] = f2bf(accB[r]);
    }
    __syncthreads();

    // coalesced partial stores: thread t -> channel c = t>>2, i-quarter t&3
    {
        const int c   = t >> 2;
        const int qtr = t & 3;
        u16x8 h0, h1;
#pragma unroll
        for (int j = 0; j < 16; ++j) {
            const int q  = qtr * 16 + j;
            const int qh = q >> 5;
            const int ql = q & 31;
            const float v = bf2f(o16[(qh * 2) * 2112 + ql * 66 + c]) +
                            bf2f(o16[(qh * 2 + 1) * 2112 + ql * 66 + c]);
            if (j < 8) h0[j] = f2bf(v);
            else       h1[j - 8] = f2bf(v);
        }
        unsigned short* dst =
            nump + (((size_t)(kq * 64 + c)) << 14) + i0 + qtr * 16;
        ((uint4*)dst)[0] = __builtin_bit_cast(uint4, h0);
        ((uint4*)dst)[1] = __builtin_bit_cast(uint4, h1);
        if (t < 64) denp[kq * NPOS + i0 + t] = den_s[t];
    }
}

// ---------------------------------------------------------------------------
__global__ __launch_bounds__(256) void finalize_kernel(
    const float* __restrict__ x,
    const unsigned short* __restrict__ nump,
    const float* __restrict__ denp,
    const float* __restrict__ gamma,
    float* __restrict__ out)
{
    const int idx = blockIdx.x * 256 + threadIdx.x;   // over 64*NPOS
    const int n   = idx & (NPOS - 1);
    const int c   = idx >> 14;
    float ns = 0.f, ds = 0.f;
#pragma unroll
    for (int kq = 0; kq < 8; ++kq) {
        ns += bf2f(nump[(((size_t)(kq * 64 + c)) << 14) + n]);
        ds += denp[kq * NPOS + n];
    }
    out[idx] = fmaf(gamma[0], ns * __builtin_amdgcn_rcpf(ds), x[idx]);
}

// ---------------------------------------------------------------------------
extern "C" void kernel_launch(void* const* d_in, const int* in_sizes, int n_in,
                              void* d_out, int out_size, void* d_ws, size_t ws_size,
                              hipStream_t stream)
{
    (void)in_sizes; (void)n_in; (void)out_size; (void)ws_size;

    const float* x     = (const float*)d_in[0];
    const float* wq    = (const float*)d_in[1];
    const float* bq    = (const float*)d_in[2];
    const float* wk    = (const float*)d_in[3];
    const float* bk    = (const float*)d_in[4];
    const float* wv    = (const float*)d_in[5];
    const float* bv    = (const float*)d_in[6];
    const float* gamma = (const float*)d_in[7];
    float* out = (float*)d_out;

    char* ws = (char*)d_ws;
    unsigned short* qb16 = (unsigned short*)(ws);               // 256 KB
    unsigned short* kb16 = (unsigned short*)(ws + 262144);      // 256 KB
    unsigned short* vb16 = (unsigned short*)(ws + 524288);      // 2 MB
    unsigned short* nump = (unsigned short*)(ws + 2621440);     // 16 MB bf16
    float*          denp = (float*)(ws + 19398656);             // 512 KB

    proj_kernel<<<dim3(NPOS / 256, 5), 256, 0, stream>>>(
        x, wq, bq, wk, bk, wv, bv, qb16, kb16, vb16);
    attn_kernel<<<(NPOS / 64) * KSPLIT, 256, 0, stream>>>(
        (const uint4*)qb16, (const uint4*)kb16, (const uint4*)vb16,
        nump, denp);
    finalize_kernel<<<(64 * NPOS) / 256, 256, 0, stream>>>(x, nump, denp,
                                                           gamma, out);
}